// Round 2
// baseline (718.057 us; speedup 1.0000x reference)
//
#include <hip/hip_runtime.h>

#define HW 4096
#define CC 256
#define CQ 32
#define NB 4
#define QBLK 32
#define KBLK 32

// ---------------- Stage 1: fused 1x1-conv projections ----------------
// Computes q[n][32][HW], k[n][32][HW], vT[n][HW][256] (V stored transposed).
// Output-channel space och in [0,320): 0..31 -> q, 32..63 -> k, 64..319 -> v.
// Grid: 4 n * 64 colblocks * 5 ochblocks = 1280 blocks, 256 threads.
// Per block: 64 cols x 64 och tile, 4x4 per thread, x and W^T staged in LDS.
__global__ __launch_bounds__(256) void qkv_kernel(
    const float* __restrict__ x,
    const float* __restrict__ Wq, const float* __restrict__ bq,
    const float* __restrict__ Wk, const float* __restrict__ bk,
    const float* __restrict__ Wv, const float* __restrict__ bv,
    float* __restrict__ q, float* __restrict__ k, float* __restrict__ vT)
{
    __shared__ float xs[32][64];   // x tile [c-sub][col]
    __shared__ float ws[32][68];   // W^T tile [c-sub][och], pad to 68 (16B-mult rows)

    const int t = threadIdx.x;
    const int b = blockIdx.x;
    const int n  = b / 320;
    const int r  = b % 320;
    const int cb = r / 5;          // column block (64 cols)
    const int ob = r % 5;          // och block (64 channels)
    const int col0 = cb * 64;
    const int och0 = ob * 64;

    const int colg = t & 15;       // 16 col-groups of 4
    const int ochg = t >> 4;       // 16 och-groups of 4

    float acc[4][4] = {};          // [oi][ci]

    for (int ct = 0; ct < 8; ++ct) {
        __syncthreads();
        // stage x[ct*32 .. +32][col0 .. +64]
        #pragma unroll
        for (int i = 0; i < 8; ++i) {
            int idx = t + i * 256;
            int cc = idx >> 6, col = idx & 63;
            xs[cc][col] = x[(n * CC + ct * 32 + cc) * HW + col0 + col];
        }
        // stage W^T: ws[cc][och] = W[och0+och][ct*32+cc] (coalesced read, LDS transpose)
        #pragma unroll
        for (int i = 0; i < 8; ++i) {
            int idx = t + i * 256;
            int och = idx >> 5, cc = idx & 31;
            int oo = och0 + och;
            int c  = ct * 32 + cc;
            float w;
            if (oo < 32)       w = Wq[oo * CC + c];
            else if (oo < 64)  w = Wk[(oo - 32) * CC + c];
            else               w = Wv[(oo - 64) * CC + c];
            ws[cc][och] = w;
        }
        __syncthreads();
        #pragma unroll
        for (int cc = 0; cc < 32; ++cc) {
            float4 xv4 = *(const float4*)&xs[cc][colg * 4];
            float4 wv4 = *(const float4*)&ws[cc][ochg * 4];
            float xv[4] = {xv4.x, xv4.y, xv4.z, xv4.w};
            float wv[4] = {wv4.x, wv4.y, wv4.z, wv4.w};
            #pragma unroll
            for (int oi = 0; oi < 4; ++oi)
                #pragma unroll
                for (int ci = 0; ci < 4; ++ci)
                    acc[oi][ci] += wv[oi] * xv[ci];
        }
    }

    const int och_base = och0 + ochg * 4;
    float bias[4];
    #pragma unroll
    for (int oi = 0; oi < 4; ++oi) {
        int oo = och_base + oi;
        bias[oi] = (oo < 32) ? bq[oo] : (oo < 64) ? bk[oo - 32] : bv[oo - 64];
    }

    if (och_base < 64) {
        // q or k: layout [n][32][HW], contiguous in col
        #pragma unroll
        for (int oi = 0; oi < 4; ++oi) {
            int oo = och_base + oi;
            float4 val = make_float4(acc[oi][0] + bias[oi], acc[oi][1] + bias[oi],
                                     acc[oi][2] + bias[oi], acc[oi][3] + bias[oi]);
            float* dst = (oo < 32)
                ? (q + (size_t)(n * CQ + oo) * HW + col0 + colg * 4)
                : (k + (size_t)(n * CQ + (oo - 32)) * HW + col0 + colg * 4);
            *(float4*)dst = val;
        }
    } else {
        // v: transposed layout vT[n][col][256], contiguous in channel
        int cv0 = och_base - 64;
        #pragma unroll
        for (int ci = 0; ci < 4; ++ci) {
            int col = col0 + colg * 4 + ci;
            float4 val = make_float4(acc[0][ci] + bias[0], acc[1][ci] + bias[1],
                                     acc[2][ci] + bias[2], acc[3][ci] + bias[3]);
            *(float4*)&vT[((size_t)n * HW + col) * CC + cv0] = val;
        }
    }
}

// ---------------- Stage 2: flash attention + gamma*out + x ----------------
// Grid: 4 n * 128 q-blocks = 512 blocks, 256 threads (4 waves).
// Per j-tile (32 keys): stage k(32x32) + vT rows(32x256) in LDS, compute S^T,
// wave-parallel online softmax, then outer-product PV with 4qi x 8c per thread.
__global__ __launch_bounds__(256) void attn_kernel(
    const float* __restrict__ qg, const float* __restrict__ kg,
    const float* __restrict__ vTg, const float* __restrict__ x,
    const float* __restrict__ gamma_p, float* __restrict__ out)
{
    __shared__ float qs[CQ][QBLK];     // q tile [c][qi]
    __shared__ float ks[CQ][KBLK];     // k tile [c][j]
    __shared__ float st[KBLK][36];     // S^T / P^T [j][qi], padded (16B-mult rows)
    __shared__ float vs[KBLK][260];    // vT rows [j][c], pad 4 (16B-mult rows)
    __shared__ float m_run[QBLK], l_run[QBLK], alpha_s[QBLK];

    const int t = threadIdx.x;
    const int b = blockIdx.x;
    const int n  = b >> 7;
    const int qb = b & 127;
    const int q0 = qb * QBLK;

    // load q tile (coalesced)
    {
        int qi = t & 31, c = t >> 5;
        #pragma unroll
        for (int i = 0; i < 4; ++i)
            qs[c + i * 8][qi] = qg[(size_t)(n * CQ + c + i * 8) * HW + q0 + qi];
    }
    if (t < QBLK) { m_run[t] = -1e30f; l_run[t] = 0.0f; }

    float acc[4][8] = {};              // [qi][c]: c in {c0..c0+3, c0+128..+131}
    const int qi4 = (t >> 5) * 4;      // 0..28
    const int c0  = (t & 31) * 4;      // 0..124

    for (int jt = 0; jt < HW / KBLK; ++jt) {
        const int j0 = jt * KBLK;
        __syncthreads();               // prev PV done; safe to overwrite ks/vs
        // stage k tile
        {
            int jj = t & 31, c = t >> 5;
            #pragma unroll
            for (int i = 0; i < 4; ++i)
                ks[c + i * 8][jj] = kg[(size_t)(n * CQ + c + i * 8) * HW + j0 + jj];
        }
        // stage vT rows (32 x 256)
        #pragma unroll
        for (int i = 0; i < 32; ++i) {
            int idx = t + i * 256;
            int jj = idx >> 8, c = idx & 255;
            vs[jj][c] = vTg[((size_t)n * HW + j0 + jj) * CC + c];
        }
        __syncthreads();
        // S^T compute: thread owns (j = t&31, 4 consecutive qi)
        {
            int j = t & 31;
            int qq = (t >> 5) * 4;
            float s0 = 0, s1 = 0, s2 = 0, s3 = 0;
            #pragma unroll
            for (int c = 0; c < 32; ++c) {
                float kv = ks[c][j];
                s0 += qs[c][qq + 0] * kv;
                s1 += qs[c][qq + 1] * kv;
                s2 += qs[c][qq + 2] * kv;
                s3 += qs[c][qq + 3] * kv;
            }
            *(float4*)&st[j][qq] = make_float4(s0, s1, s2, s3);
        }
        __syncthreads();
        // online-softmax stats: 8 lanes per query row (wave-parallel)
        {
            int qi = t >> 3, jg = t & 7;
            float v0 = st[jg][qi], v1 = st[jg + 8][qi];
            float v2 = st[jg + 16][qi], v3 = st[jg + 24][qi];
            float mt = fmaxf(fmaxf(v0, v1), fmaxf(v2, v3));
            mt = fmaxf(mt, __shfl_xor(mt, 1));
            mt = fmaxf(mt, __shfl_xor(mt, 2));
            mt = fmaxf(mt, __shfl_xor(mt, 4));
            float mo = m_run[qi];
            float mn = fmaxf(mo, mt);
            float e0 = __expf(v0 - mn), e1 = __expf(v1 - mn);
            float e2 = __expf(v2 - mn), e3 = __expf(v3 - mn);
            st[jg][qi] = e0; st[jg + 8][qi] = e1;
            st[jg + 16][qi] = e2; st[jg + 24][qi] = e3;
            float ls = e0 + e1 + e2 + e3;
            ls += __shfl_xor(ls, 1);
            ls += __shfl_xor(ls, 2);
            ls += __shfl_xor(ls, 4);
            if (jg == 0) {
                float alpha = __expf(mo - mn);
                l_run[qi] = l_run[qi] * alpha + ls;
                m_run[qi] = mn;
                alpha_s[qi] = alpha;
            }
        }
        __syncthreads();
        // rescale + PV outer product
        {
            float a[4] = {alpha_s[qi4], alpha_s[qi4 + 1], alpha_s[qi4 + 2], alpha_s[qi4 + 3]};
            #pragma unroll
            for (int u = 0; u < 4; ++u)
                #pragma unroll
                for (int w = 0; w < 8; ++w) acc[u][w] *= a[u];
            #pragma unroll
            for (int j = 0; j < KBLK; ++j) {
                float4 p4 = *(const float4*)&st[j][qi4];
                float4 va = *(const float4*)&vs[j][c0];
                float4 vb = *(const float4*)&vs[j][c0 + 128];
                float p[4] = {p4.x, p4.y, p4.z, p4.w};
                float vv[8] = {va.x, va.y, va.z, va.w, vb.x, vb.y, vb.z, vb.w};
                #pragma unroll
                for (int u = 0; u < 4; ++u)
                    #pragma unroll
                    for (int w = 0; w < 8; ++w)
                        acc[u][w] += p[u] * vv[w];
            }
        }
    }

    // epilogue: out = gamma * (O / l) + x, vectorized over qi
    const float g = gamma_p[0];
    float il[4] = {1.0f / l_run[qi4], 1.0f / l_run[qi4 + 1],
                   1.0f / l_run[qi4 + 2], 1.0f / l_run[qi4 + 3]};
    #pragma unroll
    for (int h = 0; h < 2; ++h) {
        #pragma unroll
        for (int w = 0; w < 4; ++w) {
            int c = c0 + h * 128 + w;
            size_t addr = (size_t)(n * CC + c) * HW + q0 + qi4;
            float4 x4 = *(const float4*)&x[addr];
            float4 o4 = make_float4(
                g * acc[0][h * 4 + w] * il[0] + x4.x,
                g * acc[1][h * 4 + w] * il[1] + x4.y,
                g * acc[2][h * 4 + w] * il[2] + x4.z,
                g * acc[3][h * 4 + w] * il[3] + x4.w);
            *(float4*)&out[addr] = o4;
        }
    }
}

extern "C" void kernel_launch(void* const* d_in, const int* in_sizes, int n_in,
                              void* d_out, int out_size, void* d_ws, size_t ws_size,
                              hipStream_t stream) {
    const float* x  = (const float*)d_in[0];
    const float* Wq = (const float*)d_in[1];
    const float* bq = (const float*)d_in[2];
    const float* Wk = (const float*)d_in[3];
    const float* bk = (const float*)d_in[4];
    const float* Wv = (const float*)d_in[5];
    const float* bv = (const float*)d_in[6];
    const float* gm = (const float*)d_in[7];
    float* out = (float*)d_out;

    float* q  = (float*)d_ws;                       // 4*32*4096
    float* k  = q + (size_t)NB * CQ * HW;           // 4*32*4096
    float* vT = k + (size_t)NB * CQ * HW;           // 4*4096*256

    hipLaunchKernelGGL(qkv_kernel, dim3(1280), dim3(256), 0, stream,
                       x, Wq, bq, Wk, bk, Wv, bv, q, k, vT);
    hipLaunchKernelGGL(attn_kernel, dim3(512), dim3(256), 0, stream,
                       q, k, vT, x, gm, out);
}

// Round 3
// 201.028 us; speedup vs baseline: 3.5719x; 3.5719x over previous
//
#include <hip/hip_runtime.h>

#define HWA 4096
#define CCH 256
#define CQH 32
#define NBATCH 4
#define QB 64
#define KB 128

typedef __attribute__((ext_vector_type(8))) short bf16x8;
typedef __attribute__((ext_vector_type(4))) float f32x4;

__device__ __forceinline__ unsigned short f2bf(float f) {
    union { float f; unsigned u; } a; a.f = f;
    unsigned r = a.u + 0x7FFFu + ((a.u >> 16) & 1u);
    return (unsigned short)(r >> 16);
}
__device__ __forceinline__ float bf2f(unsigned short h) {
    union { unsigned u; float f; } a; a.u = ((unsigned)h) << 16;
    return a.f;
}

// ---------------- Stage 1: fused 1x1-conv projections ----------------
// Outputs: qhi/qlo/khi/klo [n][hw][32] bf16 (hi/lo split), vb [n][c][hw] bf16.
// Grid: 4n * 64 colblocks * 5 ochblocks = 1280 blocks, 256 threads.
__global__ __launch_bounds__(256) void qkv_kernel(
    const float* __restrict__ x,
    const float* __restrict__ Wq, const float* __restrict__ bq,
    const float* __restrict__ Wk, const float* __restrict__ bk,
    const float* __restrict__ Wv, const float* __restrict__ bv,
    unsigned short* __restrict__ qhi, unsigned short* __restrict__ qlo,
    unsigned short* __restrict__ khi, unsigned short* __restrict__ klo,
    unsigned short* __restrict__ vb)
{
    __shared__ float xs[32][64];
    __shared__ float ws[32][68];

    const int t = threadIdx.x;
    const int b = blockIdx.x;
    const int n  = b / 320;
    const int r  = b % 320;
    const int cb = r / 5;
    const int ob = r % 5;
    const int col0 = cb * 64;
    const int och0 = ob * 64;

    const int colg = t & 15;
    const int ochg = t >> 4;

    float acc[4][4] = {};   // [oi][ci]

    for (int ct = 0; ct < 8; ++ct) {
        __syncthreads();
        #pragma unroll
        for (int i = 0; i < 8; ++i) {
            int idx = t + i * 256;
            int cc = idx >> 6, col = idx & 63;
            xs[cc][col] = x[(n * CCH + ct * 32 + cc) * HWA + col0 + col];
        }
        #pragma unroll
        for (int i = 0; i < 8; ++i) {
            int idx = t + i * 256;
            int och = idx >> 5, cc = idx & 31;
            int oo = och0 + och;
            int c  = ct * 32 + cc;
            float w;
            if (oo < 32)       w = Wq[oo * CCH + c];
            else if (oo < 64)  w = Wk[(oo - 32) * CCH + c];
            else               w = Wv[(oo - 64) * CCH + c];
            ws[cc][och] = w;
        }
        __syncthreads();
        #pragma unroll
        for (int cc = 0; cc < 32; ++cc) {
            float4 xv4 = *(const float4*)&xs[cc][colg * 4];
            float4 wv4 = *(const float4*)&ws[cc][ochg * 4];
            float xv[4] = {xv4.x, xv4.y, xv4.z, xv4.w};
            float wv[4] = {wv4.x, wv4.y, wv4.z, wv4.w};
            #pragma unroll
            for (int oi = 0; oi < 4; ++oi)
                #pragma unroll
                for (int ci = 0; ci < 4; ++ci)
                    acc[oi][ci] += wv[oi] * xv[ci];
        }
    }

    const int och_base = och0 + ochg * 4;
    const int col_base = col0 + colg * 4;
    float bias[4];
    #pragma unroll
    for (int oi = 0; oi < 4; ++oi) {
        int oo = och_base + oi;
        bias[oi] = (oo < 32) ? bq[oo] : (oo < 64) ? bk[oo - 32] : bv[oo - 64];
    }

    if (och_base < 64) {
        // q or k: [n][hw][32] hi/lo split; 4 consecutive och per col -> ushort4
        const bool isq = (och_base < 32);
        unsigned short* hi_p = isq ? qhi : khi;
        unsigned short* lo_p = isq ? qlo : klo;
        int oc = isq ? och_base : (och_base - 32);
        #pragma unroll
        for (int ci = 0; ci < 4; ++ci) {
            int col = col_base + ci;
            ushort4 h, lo;
            float vh[4];
            #pragma unroll
            for (int oi = 0; oi < 4; ++oi) {
                float v = acc[oi][ci] + bias[oi];
                unsigned short hb = f2bf(v);
                vh[oi] = bf2f(hb);
                ((unsigned short*)&h)[oi]  = hb;
                ((unsigned short*)&lo)[oi] = f2bf(v - vh[oi]);
            }
            size_t base = ((size_t)(n * HWA + col)) * 32 + oc;
            *(ushort4*)(hi_p + base) = h;
            *(ushort4*)(lo_p + base) = lo;
        }
    } else {
        // v: [n][256][hw] bf16; 4 consecutive cols per channel -> ushort4
        #pragma unroll
        for (int oi = 0; oi < 4; ++oi) {
            int c = och_base - 64 + oi;
            ushort4 pk;
            #pragma unroll
            for (int ci = 0; ci < 4; ++ci)
                ((unsigned short*)&pk)[ci] = f2bf(acc[oi][ci] + bias[oi]);
            *(ushort4*)(vb + ((size_t)(n * CCH + c)) * HWA + col_base) = pk;
        }
    }
}

// ---------------- Stage 2: MFMA flash attention ----------------
// Grid: 256 blocks (XCD-swizzled: n = xcd/2), 512 threads (8 waves).
// Per 128-key tile: swapped S^T = mfma(K,Q) (3-term hi/lo split), cross-wave
// online softmax via LDS, P written in A-fragment order, PV = mfma(P,V).
__global__ __launch_bounds__(512) void attn_kernel(
    const unsigned short* __restrict__ qhi, const unsigned short* __restrict__ qlo,
    const unsigned short* __restrict__ khi, const unsigned short* __restrict__ klo,
    const unsigned short* __restrict__ vb,  const float* __restrict__ x,
    const float* __restrict__ gamma_p, float* __restrict__ out)
{
    __shared__ unsigned short P_lds[4 * 4 * 64 * 8];   // [m][s][lane][8] = 16KB
    __shared__ float pmax[64][9];
    __shared__ float plsum[64][9];
    __shared__ float alpha_lds[64];
    __shared__ float lrow[64];
    __shared__ float out_lds[16][265];

    const int tid = threadIdx.x;
    const int w = tid >> 6;        // wave 0..7
    const int l = tid & 63;
    const int l15 = l & 15;
    const int g = l >> 4;          // 0..3

    // XCD-grouping swizzle: 256 blocks, 8 XCDs -> XCD x gets logical [32x,32x+32)
    const int bid = blockIdx.x;
    const int logical = (bid & 7) * 32 + (bid >> 3);
    const int n  = logical >> 6;
    const int qb = logical & 63;
    const int q0 = qb * QB;

    // Q fragments (B operand): col qi = 16*nt + l15, k ch = g*8..+8
    bf16x8 Qh[4], Ql[4];
    #pragma unroll
    for (int nt = 0; nt < 4; ++nt) {
        size_t a = ((size_t)(n * HWA + q0 + 16 * nt + l15)) * 32 + g * 8;
        Qh[nt] = *(const bf16x8*)(qhi + a);
        Ql[nt] = *(const bf16x8*)(qlo + a);
    }

    // K fragment prefetch (A operand): row j = j0 + 16w + l15, k ch = g*8..+8
    bf16x8 Kh, Kl;
    {
        size_t a = ((size_t)(n * HWA + 16 * w + l15)) * 32 + g * 8;
        Kh = *(const bf16x8*)(khi + a);
        Kl = *(const bf16x8*)(klo + a);
    }

    f32x4 acc[4][2] = {};          // out[16m+4g+r][32w+16ct+l15]
    float m_run[4] = {-1e30f, -1e30f, -1e30f, -1e30f};
    float l_run[4] = {0.f, 0.f, 0.f, 0.f};
    const f32x4 zero4 = {0.f, 0.f, 0.f, 0.f};

    for (int t = 0; t < HWA / KB; ++t) {
        const int j0 = t * KB;

        // ---- phase 1: V loads, K prefetch, QK^T, partial max ----
        bf16x8 Vf[2][4];
        #pragma unroll
        for (int ct = 0; ct < 2; ++ct)
            #pragma unroll
            for (int s = 0; s < 4; ++s)
                Vf[ct][s] = *(const bf16x8*)(vb +
                    ((size_t)(n * CCH + 32 * w + 16 * ct + l15)) * HWA + j0 + 32 * s + g * 8);

        bf16x8 Kh_n, Kl_n;
        if (t < HWA / KB - 1) {
            size_t a = ((size_t)(n * HWA + j0 + KB + 16 * w + l15)) * 32 + g * 8;
            Kh_n = *(const bf16x8*)(khi + a);
            Kl_n = *(const bf16x8*)(klo + a);
        }

        f32x4 s_acc[4];
        #pragma unroll
        for (int nt = 0; nt < 4; ++nt) {
            f32x4 sa = __builtin_amdgcn_mfma_f32_16x16x32_bf16(Kh, Qh[nt], zero4, 0, 0, 0);
            sa = __builtin_amdgcn_mfma_f32_16x16x32_bf16(Kh, Ql[nt], sa, 0, 0, 0);
            sa = __builtin_amdgcn_mfma_f32_16x16x32_bf16(Kl, Qh[nt], sa, 0, 0, 0);
            s_acc[nt] = sa;
        }

        float pm[4];
        #pragma unroll
        for (int nt = 0; nt < 4; ++nt) {
            float m01 = fmaxf(s_acc[nt][0], s_acc[nt][1]);
            float m23 = fmaxf(s_acc[nt][2], s_acc[nt][3]);
            float m = fmaxf(m01, m23);
            m = fmaxf(m, __shfl_xor(m, 16));
            m = fmaxf(m, __shfl_xor(m, 32));
            pm[nt] = m;
        }
        if (l < 16) {
            #pragma unroll
            for (int nt = 0; nt < 4; ++nt) pmax[16 * nt + l][w] = pm[nt];
        }
        __syncthreads();

        // ---- phase 2: combine max, P=exp, pack+write, partial sums ----
        float mn[4], alpha[4];
        bool need = false;
        #pragma unroll
        for (int nt = 0; nt < 4; ++nt) {
            float mm = m_run[nt];
            #pragma unroll
            for (int ww = 0; ww < 8; ++ww) mm = fmaxf(mm, pmax[16 * nt + l15][ww]);
            mn[nt] = mm;
            alpha[nt] = __expf(m_run[nt] - mm);
            need = need || (mm > m_run[nt]);
            m_run[nt] = mm;
        }
        if (tid < 16) {
            #pragma unroll
            for (int nt = 0; nt < 4; ++nt) alpha_lds[16 * nt + tid] = alpha[nt];
        }

        float ps[4];
        #pragma unroll
        for (int nt = 0; nt < 4; ++nt) {
            float e0 = __expf(s_acc[nt][0] - mn[nt]);
            float e1 = __expf(s_acc[nt][1] - mn[nt]);
            float e2 = __expf(s_acc[nt][2] - mn[nt]);
            float e3 = __expf(s_acc[nt][3] - mn[nt]);
            ps[nt] = (e0 + e1) + (e2 + e3);
            unsigned u0 = (unsigned)f2bf(e0) | ((unsigned)f2bf(e1) << 16);
            unsigned u1 = (unsigned)f2bf(e2) | ((unsigned)f2bf(e3) << 16);
            // P[16nt+l15][16w+4g+r] stored in PV-A-fragment order
            char* pb = (char*)P_lds + nt * 4096 + (w >> 1) * 1024 +
                       ((2 * (w & 1) + (g >> 1)) * 16 + l15) * 16 + (g & 1) * 8;
            *(uint2*)pb = make_uint2(u0, u1);
        }
        #pragma unroll
        for (int nt = 0; nt < 4; ++nt) {
            float s = ps[nt];
            s += __shfl_xor(s, 16);
            s += __shfl_xor(s, 32);
            ps[nt] = s;
        }
        if (l < 16) {
            #pragma unroll
            for (int nt = 0; nt < 4; ++nt) plsum[16 * nt + l][w] = ps[nt];
        }
        __syncthreads();

        // ---- phase 3: l update, rescale, PV MFMA ----
        #pragma unroll
        for (int nt = 0; nt < 4; ++nt) {
            float s = 0.f;
            #pragma unroll
            for (int ww = 0; ww < 8; ++ww) s += plsum[16 * nt + l15][ww];
            l_run[nt] = l_run[nt] * alpha[nt] + s;
        }
        if (__any(need)) {                     // T13: skip when no row max moved
            #pragma unroll
            for (int m = 0; m < 4; ++m) {
                f32x4 av = *(const f32x4*)&alpha_lds[16 * m + 4 * g];
                #pragma unroll
                for (int ct = 0; ct < 2; ++ct)
                    #pragma unroll
                    for (int r = 0; r < 4; ++r)
                        acc[m][ct][r] *= av[r];
            }
        }
        #pragma unroll
        for (int s = 0; s < 4; ++s) {
            bf16x8 Af[4];
            #pragma unroll
            for (int m = 0; m < 4; ++m)
                Af[m] = *(const bf16x8*)((const char*)P_lds + (m * 4 + s) * 1024 + l * 16);
            #pragma unroll
            for (int m = 0; m < 4; ++m)
                #pragma unroll
                for (int ct = 0; ct < 2; ++ct)
                    acc[m][ct] = __builtin_amdgcn_mfma_f32_16x16x32_bf16(
                        Af[m], Vf[ct][s], acc[m][ct], 0, 0, 0);
        }
        Kh = Kh_n; Kl = Kl_n;
        __syncthreads();                       // P safe to overwrite next tile
    }

    // ---- epilogue: out = gamma*(O/l) + x, LDS-transposed coalesced ----
    if (tid < 16) {
        #pragma unroll
        for (int nt = 0; nt < 4; ++nt) lrow[16 * nt + tid] = l_run[nt];
    }
    __syncthreads();
    const float gam = gamma_p[0];
    for (int m = 0; m < 4; ++m) {
        #pragma unroll
        for (int ct = 0; ct < 2; ++ct)
            #pragma unroll
            for (int r = 0; r < 4; ++r)
                out_lds[4 * g + r][32 * w + 16 * ct + l15] = acc[m][ct][r];
        __syncthreads();
        const int qi = tid & 15;
        const int cb2 = tid >> 4;
        const float li = 1.0f / lrow[16 * m + qi];
        #pragma unroll
        for (int p = 0; p < 8; ++p) {
            int c = cb2 + 32 * p;
            size_t ga = ((size_t)(n * CCH + c)) * HWA + q0 + 16 * m + qi;
            out[ga] = gam * out_lds[qi][c] * li + x[ga];
        }
        __syncthreads();
    }
}

extern "C" void kernel_launch(void* const* d_in, const int* in_sizes, int n_in,
                              void* d_out, int out_size, void* d_ws, size_t ws_size,
                              hipStream_t stream) {
    const float* x  = (const float*)d_in[0];
    const float* Wq = (const float*)d_in[1];
    const float* bq = (const float*)d_in[2];
    const float* Wk = (const float*)d_in[3];
    const float* bk = (const float*)d_in[4];
    const float* Wv = (const float*)d_in[5];
    const float* bv = (const float*)d_in[6];
    const float* gm = (const float*)d_in[7];
    float* out = (float*)d_out;

    unsigned short* qhi = (unsigned short*)d_ws;                 // 4*4096*32
    unsigned short* qlo = qhi + (size_t)NBATCH * HWA * CQH;
    unsigned short* khi = qlo + (size_t)NBATCH * HWA * CQH;
    unsigned short* klo = khi + (size_t)NBATCH * HWA * CQH;
    unsigned short* vbp = klo + (size_t)NBATCH * HWA * CQH;      // 4*256*4096

    hipLaunchKernelGGL(qkv_kernel, dim3(1280), dim3(256), 0, stream,
                       x, Wq, bq, Wk, bk, Wv, bv, qhi, qlo, khi, klo, vbp);
    hipLaunchKernelGGL(attn_kernel, dim3(256), dim3(512), 0, stream,
                       qhi, qlo, khi, klo, vbp, x, gm, out);
}

// Round 4
// 158.293 us; speedup vs baseline: 4.5363x; 1.2700x over previous
//
#include <hip/hip_runtime.h>

#define HWA 4096
#define CCH 256
#define NBATCH 4
#define QB 64
#define KBT 128
#define NTILES (HWA / KBT)   // 32

typedef __attribute__((ext_vector_type(8))) short bf16x8;
typedef __attribute__((ext_vector_type(4))) float f32x4;

__device__ __forceinline__ unsigned short f2bf(float f) {
    union { float f; unsigned u; } a; a.f = f;
    unsigned r = a.u + 0x7FFFu + ((a.u >> 16) & 1u);
    return (unsigned short)(r >> 16);
}
__device__ __forceinline__ float bf2f(unsigned short h) {
    union { unsigned u; float f; } a; a.u = ((unsigned)h) << 16;
    return a.f;
}
// raw barrier: drain LDS ops only, keep global prefetch (vmcnt) in flight
__device__ __forceinline__ void bar_lds() {
    asm volatile("s_waitcnt lgkmcnt(0)" ::: "memory");
    __builtin_amdgcn_s_barrier();
}

// ---------------- Stage 0: pack W into A-fragment-ordered hi/lo bf16 ----------------
// whi/wlo layout: [ot 0..19][kf 0..7][lane 0..63][8]; och = ot*16 + (lane&15),
// k-channel = 32*kf + (lane>>4)*8 + j. ot 0-1:q, 2-3:k, 4-19:v. bias_all[320].
__global__ __launch_bounds__(256) void wprep_kernel(
    const float* __restrict__ Wq, const float* __restrict__ bq,
    const float* __restrict__ Wk, const float* __restrict__ bk,
    const float* __restrict__ Wv, const float* __restrict__ bv,
    unsigned short* __restrict__ whi, unsigned short* __restrict__ wlo,
    float* __restrict__ bias_all)
{
    const int ot = blockIdx.x;
    const int t = threadIdx.x;
    const int lane = t & 63;
    const int l15 = lane & 15, g = lane >> 4;
    const int och = ot * 16 + l15;
    #pragma unroll
    for (int pass = 0; pass < 2; ++pass) {
        const int kf = (t >> 6) + 4 * pass;
        unsigned short h8[8], l8[8];
        #pragma unroll
        for (int j = 0; j < 8; ++j) {
            int c = 32 * kf + g * 8 + j;
            float v;
            if (och < 32)      v = Wq[och * CCH + c];
            else if (och < 64) v = Wk[(och - 32) * CCH + c];
            else               v = Wv[(och - 64) * CCH + c];
            unsigned short hb = f2bf(v);
            h8[j] = hb;
            l8[j] = f2bf(v - bf2f(hb));
        }
        size_t base = ((size_t)(ot * 8 + kf) * 64 + lane) * 8;
        *(bf16x8*)(whi + base) = *(bf16x8*)h8;
        *(bf16x8*)(wlo + base) = *(bf16x8*)l8;
    }
    if (ot == 0) {
        for (int i = t; i < 320; i += 256)
            bias_all[i] = (i < 32) ? bq[i] : (i < 64) ? bk[i - 32] : bv[i - 64];
    }
}

// ---------------- Stage 1: MFMA projection GEMM ----------------
// Grid 256 (XCD-swizzled), 4 waves. Wave owns 16 cols, loops 20 och-tiles.
// 3-term hi/lo split MFMA (fp32-grade). No LDS.
__global__ __launch_bounds__(256) void qkvgemm_kernel(
    const float* __restrict__ x,
    const unsigned short* __restrict__ whi, const unsigned short* __restrict__ wlo,
    const float* __restrict__ bias_all,
    unsigned short* __restrict__ qhi, unsigned short* __restrict__ qlo,
    unsigned short* __restrict__ khi, unsigned short* __restrict__ klo,
    unsigned short* __restrict__ vb)
{
    const int t = threadIdx.x;
    const int w = t >> 6, l = t & 63, l15 = l & 15, g = l >> 4;
    const int b = blockIdx.x;
    const int logical = (b & 7) * 32 + (b >> 3);
    const int n  = logical >> 6;
    const int cb = logical & 63;
    const int col = cb * 64 + w * 16 + l15;

    // B fragments: x[channels][col] -> hi/lo bf16
    bf16x8 Bh[8], Bl[8];
    #pragma unroll
    for (int kf = 0; kf < 8; ++kf) {
        unsigned short hh[8], ll[8];
        #pragma unroll
        for (int j = 0; j < 8; ++j) {
            float v = x[((size_t)(n * CCH + 32 * kf + g * 8 + j)) * HWA + col];
            unsigned short hb = f2bf(v);
            hh[j] = hb;
            ll[j] = f2bf(v - bf2f(hb));
        }
        Bh[kf] = *(bf16x8*)hh;
        Bl[kf] = *(bf16x8*)ll;
    }

    const f32x4 zero4 = {0.f, 0.f, 0.f, 0.f};
    for (int ot = 0; ot < 20; ++ot) {
        f32x4 acc = zero4;
        #pragma unroll
        for (int kf = 0; kf < 8; ++kf) {
            size_t base = ((size_t)(ot * 8 + kf) * 64 + l) * 8;
            bf16x8 Ah = *(const bf16x8*)(whi + base);
            bf16x8 Al = *(const bf16x8*)(wlo + base);
            acc = __builtin_amdgcn_mfma_f32_16x16x32_bf16(Ah, Bh[kf], acc, 0, 0, 0);
            acc = __builtin_amdgcn_mfma_f32_16x16x32_bf16(Ah, Bl[kf], acc, 0, 0, 0);
            acc = __builtin_amdgcn_mfma_f32_16x16x32_bf16(Al, Bh[kf], acc, 0, 0, 0);
        }
        f32x4 bia = *(const f32x4*)&bias_all[ot * 16 + 4 * g];
        float vv[4];
        #pragma unroll
        for (int r = 0; r < 4; ++r) vv[r] = acc[r] + bia[r];

        if (ot < 4) {
            // q/k: [n][hw][32] hi/lo, rows 4g+r contiguous
            unsigned short h4[4], l4[4];
            #pragma unroll
            for (int r = 0; r < 4; ++r) {
                unsigned short hb = f2bf(vv[r]);
                h4[r] = hb;
                l4[r] = f2bf(vv[r] - bf2f(hb));
            }
            unsigned short* hp = (ot < 2) ? qhi : khi;
            unsigned short* lp = (ot < 2) ? qlo : klo;
            size_t base = ((size_t)(n * HWA + col)) * 32 + (ot & 1) * 16 + 4 * g;
            *(ushort4*)(hp + base) = *(ushort4*)h4;
            *(ushort4*)(lp + base) = *(ushort4*)l4;
        } else {
            // v: [n][256][hw] bf16
            #pragma unroll
            for (int r = 0; r < 4; ++r)
                vb[((size_t)(n * CCH + ot * 16 - 64 + 4 * g + r)) * HWA + col] = f2bf(vv[r]);
        }
    }
}

// ---------------- Stage 2: pipelined MFMA flash attention ----------------
// Grid 256 (XCD-swizzled: 2 XCDs per n), 8 waves. Per 128-key tile:
// one setprio MFMA cluster {QK(t+1), PV(t)}, 8-thread/row max combine,
// register lsum, defer-max THR=8, P double-buffered, raw barriers.
__global__ __launch_bounds__(512, 2) void attn_kernel(
    const unsigned short* __restrict__ qhi, const unsigned short* __restrict__ qlo,
    const unsigned short* __restrict__ khi, const unsigned short* __restrict__ klo,
    const unsigned short* __restrict__ vb,  const float* __restrict__ x,
    const float* __restrict__ gamma_p, float* __restrict__ out)
{
    __shared__ unsigned short P_lds[2][8192];   // 2 x 16 KB, A-frag order
    __shared__ float pmax[64][9];
    __shared__ float mrun_lds[64];
    __shared__ float alpha_lds[64];
    __shared__ float lsum_lds[64][9];
    __shared__ float out_lds[16][265];

    const int tid = threadIdx.x;
    const int w = tid >> 6;
    const int l = tid & 63;
    const int l15 = l & 15;
    const int g = l >> 4;

    const int bid = blockIdx.x;
    const int logical = (bid & 7) * 32 + (bid >> 3);
    const int n  = logical >> 6;
    const int qb = logical & 63;
    const int q0 = qb * QB;

    if (tid < 64) mrun_lds[tid] = -1e30f;

    // Q fragments (B operand): col = query q0+16nt+l15, k = channel g*8..+8
    bf16x8 Qh[4], Ql[4];
    #pragma unroll
    for (int nt = 0; nt < 4; ++nt) {
        size_t a = ((size_t)(n * HWA + q0 + 16 * nt + l15)) * 32 + g * 8;
        Qh[nt] = *(const bf16x8*)(qhi + a);
        Ql[nt] = *(const bf16x8*)(qlo + a);
    }
    // K tile0 + prefetch tile1
    bf16x8 K0h, K0l, K1h, K1l;
    {
        size_t a0 = ((size_t)(n * HWA + 16 * w + l15)) * 32 + g * 8;
        size_t a1 = ((size_t)(n * HWA + KBT + 16 * w + l15)) * 32 + g * 8;
        K0h = *(const bf16x8*)(khi + a0);
        K0l = *(const bf16x8*)(klo + a0);
        K1h = *(const bf16x8*)(khi + a1);
        K1l = *(const bf16x8*)(klo + a1);
    }
    // V tile0
    bf16x8 Vc[2][4], Vn[2][4];
    #pragma unroll
    for (int ct = 0; ct < 2; ++ct)
        #pragma unroll
        for (int s = 0; s < 4; ++s)
            Vc[ct][s] = *(const bf16x8*)(vb +
                ((size_t)(n * CCH + 32 * w + 16 * ct + l15)) * HWA + 32 * s + g * 8);

    f32x4 acc[4][2] = {};
    f32x4 s_acc[4];
    float lsum[4] = {0.f, 0.f, 0.f, 0.f};
    const f32x4 zero4 = {0.f, 0.f, 0.f, 0.f};

    // softmax phase: partial max -> combine (8 thr/row, defer THR=8) -> exp/pack/lsum
    auto softmax_phase = [&](int pb) {
        float pm[4];
        #pragma unroll
        for (int nt = 0; nt < 4; ++nt) {
            float m01 = fmaxf(s_acc[nt][0], s_acc[nt][1]);
            float m23 = fmaxf(s_acc[nt][2], s_acc[nt][3]);
            float m = fmaxf(m01, m23);
            m = fmaxf(m, __shfl_xor(m, 16));
            m = fmaxf(m, __shfl_xor(m, 32));
            pm[nt] = m;
        }
        if (l < 16) {
            #pragma unroll
            for (int nt = 0; nt < 4; ++nt) pmax[16 * nt + l][w] = pm[nt];
        }
        bar_lds();                               // A
        {
            const int row = tid >> 3, ww = tid & 7;
            float p = pmax[row][ww];
            p = fmaxf(p, __shfl_xor(p, 1));
            p = fmaxf(p, __shfl_xor(p, 2));
            p = fmaxf(p, __shfl_xor(p, 4));
            if (ww == 0) {
                float mo = mrun_lds[row];
                if (p > mo + 8.0f) {             // T13 defer-max ratchet
                    mrun_lds[row] = p;
                    alpha_lds[row] = __expf(mo - p);
                } else {
                    alpha_lds[row] = 1.0f;
                }
            }
        }
        bar_lds();                               // B
        #pragma unroll
        for (int nt = 0; nt < 4; ++nt) {
            float mn = mrun_lds[16 * nt + l15];
            float al = alpha_lds[16 * nt + l15];
            float e0 = __expf(s_acc[nt][0] - mn);
            float e1 = __expf(s_acc[nt][1] - mn);
            float e2 = __expf(s_acc[nt][2] - mn);
            float e3 = __expf(s_acc[nt][3] - mn);
            float ps = (e0 + e1) + (e2 + e3);
            ps += __shfl_xor(ps, 16);
            ps += __shfl_xor(ps, 32);
            lsum[nt] = lsum[nt] * al + ps;
            unsigned u0 = (unsigned)f2bf(e0) | ((unsigned)f2bf(e1) << 16);
            unsigned u1 = (unsigned)f2bf(e2) | ((unsigned)f2bf(e3) << 16);
            char* pbp = (char*)P_lds + pb * 16384 + nt * 4096 + (w >> 1) * 1024 +
                        ((2 * (w & 1) + (g >> 1)) * 16 + l15) * 16 + (g & 1) * 8;
            *(uint2*)pbp = make_uint2(u0, u1);
        }
    };

    // ---- prologue: tile 0 ----
    #pragma unroll
    for (int nt = 0; nt < 4; ++nt) {
        f32x4 sa = __builtin_amdgcn_mfma_f32_16x16x32_bf16(K0h, Qh[nt], zero4, 0, 0, 0);
        sa = __builtin_amdgcn_mfma_f32_16x16x32_bf16(K0h, Ql[nt], sa, 0, 0, 0);
        sa = __builtin_amdgcn_mfma_f32_16x16x32_bf16(K0l, Qh[nt], sa, 0, 0, 0);
        s_acc[nt] = sa;
    }
    softmax_phase(0);                            // writes P_lds[0]; alpha(0)=0 path
    bar_lds();                                   // C: P(0) visible

    // ---- main loop: iter t does {QK(t+1), PV(t)} ----
    for (int t = 0; t < NTILES - 1; ++t) {
        // prefetch issues (stay in flight across raw barriers)
        if (t + 2 < NTILES) {
            size_t a = ((size_t)(n * HWA + (t + 2) * KBT + 16 * w + l15)) * 32 + g * 8;
            // K2 into K0 regs (K0 dead after prologue / previous swap)
            K0h = *(const bf16x8*)(khi + a);
            K0l = *(const bf16x8*)(klo + a);
        }
        #pragma unroll
        for (int ct = 0; ct < 2; ++ct)
            #pragma unroll
            for (int s = 0; s < 4; ++s)
                Vn[ct][s] = *(const bf16x8*)(vb +
                    ((size_t)(n * CCH + 32 * w + 16 * ct + l15)) * HWA +
                    (t + 1) * KBT + 32 * s + g * 8);

        __builtin_amdgcn_s_setprio(1);
        // QK(t+1)
        #pragma unroll
        for (int nt = 0; nt < 4; ++nt) {
            f32x4 sa = __builtin_amdgcn_mfma_f32_16x16x32_bf16(K1h, Qh[nt], zero4, 0, 0, 0);
            sa = __builtin_amdgcn_mfma_f32_16x16x32_bf16(K1h, Ql[nt], sa, 0, 0, 0);
            sa = __builtin_amdgcn_mfma_f32_16x16x32_bf16(K1l, Qh[nt], sa, 0, 0, 0);
            s_acc[nt] = sa;
        }
        // PV(t): reads P_lds[t&1] + Vc
        #pragma unroll
        for (int s = 0; s < 4; ++s) {
            bf16x8 Af[4];
            #pragma unroll
            for (int m = 0; m < 4; ++m)
                Af[m] = *(const bf16x8*)((const char*)P_lds + (t & 1) * 16384 +
                                         (m * 4 + s) * 1024 + l * 16);
            #pragma unroll
            for (int m = 0; m < 4; ++m)
                #pragma unroll
                for (int ct = 0; ct < 2; ++ct)
                    acc[m][ct] = __builtin_amdgcn_mfma_f32_16x16x32_bf16(
                        Af[m], Vc[ct][s], acc[m][ct], 0, 0, 0);
        }
        __builtin_amdgcn_s_setprio(0);

        softmax_phase((t + 1) & 1);              // bars A,B inside; writes P(t+1)

        // rescale O by alpha(t+1) (after PV(t); scoreboard orders on acc)
        #pragma unroll
        for (int m = 0; m < 4; ++m) {
            f32x4 av = *(const f32x4*)&alpha_lds[16 * m + 4 * g];
            #pragma unroll
            for (int ct = 0; ct < 2; ++ct)
                #pragma unroll
                for (int r = 0; r < 4; ++r)
                    acc[m][ct][r] *= av[r];
        }
        bar_lds();                               // C: P(t+1) visible
        K1h = K0h; K1l = K0l;
        #pragma unroll
        for (int ct = 0; ct < 2; ++ct)
            #pragma unroll
            for (int s = 0; s < 4; ++s) Vc[ct][s] = Vn[ct][s];
    }

    // ---- epilogue: PV(31) ----
    __builtin_amdgcn_s_setprio(1);
    #pragma unroll
    for (int s = 0; s < 4; ++s) {
        bf16x8 Af[4];
        #pragma unroll
        for (int m = 0; m < 4; ++m)
            Af[m] = *(const bf16x8*)((const char*)P_lds + ((NTILES - 1) & 1) * 16384 +
                                     (m * 4 + s) * 1024 + l * 16);
        #pragma unroll
        for (int m = 0; m < 4; ++m)
            #pragma unroll
            for (int ct = 0; ct < 2; ++ct)
                acc[m][ct] = __builtin_amdgcn_mfma_f32_16x16x32_bf16(
                    Af[m], Vc[ct][s], acc[m][ct], 0, 0, 0);
    }
    __builtin_amdgcn_s_setprio(0);

    if (l < 16) {
        #pragma unroll
        for (int nt = 0; nt < 4; ++nt) lsum_lds[16 * nt + l][w] = lsum[nt];
    }
    bar_lds();

    const float gam = gamma_p[0];
    for (int m = 0; m < 4; ++m) {
        #pragma unroll
        for (int ct = 0; ct < 2; ++ct)
            #pragma unroll
            for (int r = 0; r < 4; ++r)
                out_lds[4 * g + r][32 * w + 16 * ct + l15] = acc[m][ct][r];
        bar_lds();
        const int qi = tid & 15;
        const int cb2 = tid >> 4;
        float lt = 0.f;
        #pragma unroll
        for (int ww = 0; ww < 8; ++ww) lt += lsum_lds[16 * m + qi][ww];
        const float li = 1.0f / lt;
        #pragma unroll
        for (int p = 0; p < 8; ++p) {
            int c = cb2 + 32 * p;
            size_t ga = ((size_t)(n * CCH + c)) * HWA + q0 + 16 * m + qi;
            out[ga] = gam * out_lds[qi][c] * li + x[ga];
        }
        bar_lds();
    }
}

extern "C" void kernel_launch(void* const* d_in, const int* in_sizes, int n_in,
                              void* d_out, int out_size, void* d_ws, size_t ws_size,
                              hipStream_t stream) {
    const float* x  = (const float*)d_in[0];
    const float* Wq = (const float*)d_in[1];
    const float* bq = (const float*)d_in[2];
    const float* Wk = (const float*)d_in[3];
    const float* bk = (const float*)d_in[4];
    const float* Wv = (const float*)d_in[5];
    const float* bv = (const float*)d_in[6];
    const float* gm = (const float*)d_in[7];
    float* out = (float*)d_out;

    float* bias_all = (float*)d_ws;                               // 320 f
    unsigned short* whi = (unsigned short*)(bias_all + 320);      // 81920
    unsigned short* wlo = whi + 81920;
    unsigned short* qhi = wlo + 81920;                            // 16B-aligned
    unsigned short* qlo = qhi + (size_t)NBATCH * HWA * 32;
    unsigned short* khi = qlo + (size_t)NBATCH * HWA * 32;
    unsigned short* klo = khi + (size_t)NBATCH * HWA * 32;
    unsigned short* vbp = klo + (size_t)NBATCH * HWA * 32;        // 4*256*4096

    hipLaunchKernelGGL(wprep_kernel, dim3(20), dim3(256), 0, stream,
                       Wq, bq, Wk, bk, Wv, bv, whi, wlo, bias_all);
    hipLaunchKernelGGL(qkvgemm_kernel, dim3(256), dim3(256), 0, stream,
                       x, whi, wlo, bias_all, qhi, qlo, khi, klo, vbp);
    hipLaunchKernelGGL(attn_kernel, dim3(256), dim3(512), 0, stream,
                       qhi, qlo, khi, klo, vbp, x, gm, out);
}